// Round 4
// baseline (21.924 us; speedup 1.0000x reference)
//
#include <hip/hip_runtime.h>

// GRU single-step cell over N = B*A independent rows of 9 floats (col0 = h, cols1:9 = x).
// Round-4: same as R3 discriminator (RPT=8, no LDS, nontemporal stores) with the
// nontemporal builtin fixed to use a clang native vector type.

constexpr int BLOCK = 256;
constexpr int RPT   = 8;                  // rows per thread
constexpr int F4PT  = RPT * 9 / 4;        // 18 float4 loads per thread (72 floats)

typedef float nfloat4 __attribute__((ext_vector_type(4)));   // native vec for builtins

__global__ __launch_bounds__(BLOCK) void gru_cell_kernel(
    const float* __restrict__ in,    // (N, 9)
    const float* __restrict__ w_ih,  // (3, 8)
    const float* __restrict__ w_hh,  // (3, 1)
    const float* __restrict__ b_ih,  // (3,)
    const float* __restrict__ b_hh,  // (3,)
    const float* __restrict__ w_out, // (1, 1)
    const float* __restrict__ b_out, // (1,)
    float* __restrict__ out,         // (N,)
    int n_rows)
{
    const int tid = blockIdx.x * blockDim.x + threadIdx.x;
    const int row0 = tid * RPT;
    if (row0 >= n_rows) return;

    // Issue all 18 loads back-to-back (ILP; compiler keeps them in flight).
    nfloat4 v[F4PT];
    const nfloat4* src = reinterpret_cast<const nfloat4*>(in + (size_t)row0 * 9);
#pragma unroll
    for (int i = 0; i < F4PT; ++i) v[i] = src[i];

    // Uniform-address weight loads (SGPR-broadcast via s_load).
    float wih[3][8];
#pragma unroll
    for (int g = 0; g < 3; ++g)
#pragma unroll
        for (int c = 0; c < 8; ++c)
            wih[g][c] = w_ih[g * 8 + c];
    const float whh0 = w_hh[0], whh1 = w_hh[1], whh2 = w_hh[2];
    const float bi0 = b_ih[0], bi1 = b_ih[1], bi2 = b_ih[2];
    const float bh0 = b_hh[0], bh1 = b_hh[1], bh2 = b_hh[2];
    const float wo = w_out[0], bo = b_out[0];

    const float* f = reinterpret_cast<const float*>(v);
    nfloat4 o[2];
    float* op = reinterpret_cast<float*>(o);
#pragma unroll
    for (int r = 0; r < RPT; ++r) {
        const float* row = f + r * 9;   // compile-time indices after unroll
        const float h = row[0];
        float gi0 = bi0, gi1 = bi1, gi2 = bi2;
#pragma unroll
        for (int c = 0; c < 8; ++c) {
            const float x = row[1 + c];
            gi0 = fmaf(x, wih[0][c], gi0);
            gi1 = fmaf(x, wih[1][c], gi1);
            gi2 = fmaf(x, wih[2][c], gi2);
        }
        const float gh0 = fmaf(h, whh0, bh0);
        const float gh1 = fmaf(h, whh1, bh1);
        const float gh2 = fmaf(h, whh2, bh2);

        const float rg = 1.0f / (1.0f + __expf(-(gi0 + gh0)));
        const float z  = 1.0f / (1.0f + __expf(-(gi1 + gh1)));
        const float y  = fmaf(rg, gh2, gi2);
        const float nn = 2.0f / (1.0f + __expf(-2.0f * y)) - 1.0f;   // tanh(y)
        const float hn = (1.0f - z) * nn + z * h;
        op[r] = fmaf(hn, wo, bo);
    }

    // Streaming output: 2x nontemporal float4 stores (native vector type).
    nfloat4* dst = reinterpret_cast<nfloat4*>(out + row0);
    __builtin_nontemporal_store(o[0], dst);
    __builtin_nontemporal_store(o[1], dst + 1);
}

extern "C" void kernel_launch(void* const* d_in, const int* in_sizes, int n_in,
                              void* d_out, int out_size, void* d_ws, size_t ws_size,
                              hipStream_t stream) {
    (void)n_in; (void)d_ws; (void)ws_size; (void)in_sizes;
    const float* in    = (const float*)d_in[0];
    const float* w_ih  = (const float*)d_in[1];
    const float* w_hh  = (const float*)d_in[2];
    const float* b_ih  = (const float*)d_in[3];
    const float* b_hh  = (const float*)d_in[4];
    const float* w_out = (const float*)d_in[5];
    const float* b_out = (const float*)d_in[6];
    float* out = (float*)d_out;

    const int n_rows = out_size;                       // 2,097,152 (divisible by 2048)
    const int threads = n_rows / RPT;                  // 262,144
    const int grid = (threads + BLOCK - 1) / BLOCK;    // 1024

    gru_cell_kernel<<<grid, BLOCK, 0, stream>>>(in, w_ih, w_hh, b_ih, b_hh,
                                                w_out, b_out, out, n_rows);
}

// Round 5
// 18.747 us; speedup vs baseline: 1.1694x; 1.1694x over previous
//
#include <hip/hip_runtime.h>

// GRU single-step cell over N = B*A independent rows of 9 floats (col0 = h, cols1:9 = x).
// R5: coalesced global float4 loads -> LINEAR ds_write_b128 -> UNPADDED
// 144B-stride ds_read_b128 (bank-optimal: 256 words / 32 banks = 8/bank,
// same as linear). R2's mistake was +1-pad forcing scalar LDS ops.

constexpr int BLOCK = 256;
constexpr int RPT   = 4;                  // rows per thread
constexpr int RPB   = BLOCK * RPT;        // 1024 rows per block
constexpr int F4PB  = RPB * 9 / 4;        // 2304 float4 per block
constexpr int F4PT  = F4PB / BLOCK;       // 9 coalesced float4 loads per thread

typedef float nfloat4 __attribute__((ext_vector_type(4)));

__global__ __launch_bounds__(BLOCK) void gru_cell_kernel(
    const float* __restrict__ in,    // (N, 9)
    const float* __restrict__ w_ih,  // (3, 8)
    const float* __restrict__ w_hh,  // (3, 1)
    const float* __restrict__ b_ih,  // (3,)
    const float* __restrict__ b_hh,  // (3,)
    const float* __restrict__ w_out, // (1, 1)
    const float* __restrict__ b_out, // (1,)
    float* __restrict__ out,         // (N,)
    int n_rows)
{
    __shared__ nfloat4 lds4[F4PB];        // 36,864 B -> 4 blocks/CU (16 waves/CU)

    const int t = threadIdx.x;
    const int blk = blockIdx.x;
    const size_t f4_base = (size_t)blk * F4PB;

    // ---- Stage: 9 per-instruction-coalesced global float4 -> linear b128 LDS writes ----
    const nfloat4* src = reinterpret_cast<const nfloat4*>(in);
#pragma unroll
    for (int k = 0; k < F4PT; ++k) {
        const int j = k * BLOCK + t;      // consecutive lanes -> consecutive 16B
        lds4[j] = src[f4_base + j];
    }

    // Uniform-address weight loads (SGPR-broadcast via s_load).
    float wih[3][8];
#pragma unroll
    for (int g = 0; g < 3; ++g)
#pragma unroll
        for (int c = 0; c < 8; ++c)
            wih[g][c] = w_ih[g * 8 + c];
    const float whh0 = w_hh[0], whh1 = w_hh[1], whh2 = w_hh[2];
    const float bi0 = b_ih[0], bi1 = b_ih[1], bi2 = b_ih[2];
    const float bh0 = b_hh[0], bh1 = b_hh[1], bh2 = b_hh[2];
    const float wo = w_out[0], bo = b_out[0];

    __syncthreads();

    // ---- Compute: thread t reads float4s 9t..9t+8 (144B lane-stride b128, bank-clean) ----
    nfloat4 v[F4PT];
#pragma unroll
    for (int i = 0; i < F4PT; ++i) v[i] = lds4[t * F4PT + i];
    const float* f = reinterpret_cast<const float*>(v);

    nfloat4 o;
    float* op = reinterpret_cast<float*>(&o);
#pragma unroll
    for (int r = 0; r < RPT; ++r) {
        const float* row = f + r * 9;     // compile-time indices after unroll
        const float h = row[0];
        float gi0 = bi0, gi1 = bi1, gi2 = bi2;
#pragma unroll
        for (int c = 0; c < 8; ++c) {
            const float x = row[1 + c];
            gi0 = fmaf(x, wih[0][c], gi0);
            gi1 = fmaf(x, wih[1][c], gi1);
            gi2 = fmaf(x, wih[2][c], gi2);
        }
        const float gh0 = fmaf(h, whh0, bh0);
        const float gh1 = fmaf(h, whh1, bh1);
        const float gh2 = fmaf(h, whh2, bh2);

        const float rg = 1.0f / (1.0f + __expf(-(gi0 + gh0)));
        const float z  = 1.0f / (1.0f + __expf(-(gi1 + gh1)));
        const float y  = fmaf(rg, gh2, gi2);
        const float nn = 2.0f / (1.0f + __expf(-2.0f * y)) - 1.0f;   // tanh(y)
        const float hn = (1.0f - z) * nn + z * h;
        op[r] = fmaf(hn, wo, bo);
    }

    // ---- Coalesced float4 store: thread t writes rows 4t..4t+3 ----
    const size_t out_f4 = (size_t)blk * BLOCK + t;
    if ((out_f4 + 1) * 4 <= (size_t)n_rows)
        reinterpret_cast<nfloat4*>(out)[out_f4] = o;
}

extern "C" void kernel_launch(void* const* d_in, const int* in_sizes, int n_in,
                              void* d_out, int out_size, void* d_ws, size_t ws_size,
                              hipStream_t stream) {
    (void)n_in; (void)d_ws; (void)ws_size; (void)in_sizes;
    const float* in    = (const float*)d_in[0];
    const float* w_ih  = (const float*)d_in[1];
    const float* w_hh  = (const float*)d_in[2];
    const float* b_ih  = (const float*)d_in[3];
    const float* b_hh  = (const float*)d_in[4];
    const float* w_out = (const float*)d_in[5];
    const float* b_out = (const float*)d_in[6];
    float* out = (float*)d_out;

    const int n_rows = out_size;                  // B*A = 2,097,152 (divisible by 1024)
    const int grid = (n_rows + RPB - 1) / RPB;    // 2048 blocks

    gru_cell_kernel<<<grid, BLOCK, 0, stream>>>(in, w_ih, w_hh, b_ih, b_hh,
                                                w_out, b_out, out, n_rows);
}